// Round 9
// baseline (115.814 us; speedup 1.0000x reference)
//
#include <hip/hip_runtime.h>
#include <hip/hip_bf16.h>

#define FDIM 80
#define RDIM 20
#define NSLOT 6      // u64 slots per atom row: 24 x 16-bit fields (20 aev + deg + 3 pad)
#define LDSW 104     // LDS row stride (bf16)
#define WROW 96      // Wt row stride (bf16), K padded to 96

#define FIX_SCALE 512.0f        // 2^9
#define FIX_INV   0.001953125f  // 2^-9

typedef float  f32x4  __attribute__((ext_vector_type(4)));
typedef short  bf16x8 __attribute__((ext_vector_type(8)));

__device__ __forceinline__ float sp_f(float x){
  float e = __expf(-fabsf(x));
  return fmaxf(x, 0.f) + __logf(1.f + e);
}
__device__ __forceinline__ __hip_bfloat16 tob(float x){ return __float2bfloat16(x); }

// ---------------------------------------------------------------------------
// Weight prep: Wt[slot][j][k] = bf16(W[k][j]), zero-padded k in [80,96)
// ---------------------------------------------------------------------------
struct WPtrs { const float* p[21]; };

__global__ __launch_bounds__(256) void prep_weights(WPtrs wp, __hip_bfloat16* __restrict__ wt){
  const float* W = wp.p[blockIdx.x];
  __hip_bfloat16* dst = wt + (size_t)blockIdx.x * FDIM * WROW;
  for (int i = threadIdx.x; i < FDIM * WROW; i += 256){
    int j = i / WROW, k = i - j * WROW;
    dst[i] = __float2bfloat16(k < FDIM ? W[k * FDIM + j] : 0.f);
  }
}

// ---------------------------------------------------------------------------
// Scatter, 16-bit fixed-point, 4 fields per u64 (at atomic-payload floor)
// ---------------------------------------------------------------------------
__global__ __launch_bounds__(256) void scatter_p16(const float* __restrict__ aev,
    const int* __restrict__ idx12, unsigned long long* __restrict__ R6u, int P)
{
  int g = blockIdx.x * 256 + threadIdx.x;
  if (g >= P * NSLOT) return;
  int p = g / NSLOT, s = g - p * NSLOT;
  unsigned long long v;
  if (s < 5){
    float4 a = ((const float4*)(aev + (size_t)p * RDIM))[s];
    unsigned long long f0 = (unsigned long long)__float2uint_rn(a.x * FIX_SCALE);
    unsigned long long f1 = (unsigned long long)__float2uint_rn(a.y * FIX_SCALE);
    unsigned long long f2 = (unsigned long long)__float2uint_rn(a.z * FIX_SCALE);
    unsigned long long f3 = (unsigned long long)__float2uint_rn(a.w * FIX_SCALE);
    v = f0 | (f1 << 16) | (f2 << 32) | (f3 << 48);
  } else {
    v = 512ULL;   // deg increment (unpacks to 1.0)
  }
  int i1 = idx12[p], i2 = idx12[P + p];
  atomicAdd(&R6u[(size_t)i1 * NSLOT + s], v);
  atomicAdd(&R6u[(size_t)i2 * NSLOT + s], v);
}

// ---------------------------------------------------------------------------
// Per-wave weight set: 5 col-tiles x 3 K-blocks of B-frags + 5 biases
// (all indexing compile-time-unrolled -> stays in VGPRs)
// ---------------------------------------------------------------------------
struct WS { bf16x8 b[5][3]; float bias[5]; };

__device__ __forceinline__ void loadWS(WS& w, const __hip_bfloat16* __restrict__ wt,
    int slot, const float* __restrict__ bp, int j0, int kb)
{
  #pragma unroll
  for (int q = 0; q < 5; q++){
    const __hip_bfloat16* p = wt + ((size_t)slot * FDIM + 16*q + j0) * WROW + kb;
    #pragma unroll
    for (int ks = 0; ks < 3; ks++)
      w.b[q][ks] = *(const bf16x8*)(const void*)(p + 32*ks);
    w.bias[q] = bp[16*q + j0];
  }
}

// A-frag: m=lane&15, k=(lane>>4)*8+e (+32ks). C/D: col=16q+(lane&15), row=(lane>>4)*4+i.
__device__ __forceinline__ void mmA(f32x4 acc[5],
    const __hip_bfloat16 (*in)[LDSW], int j0, int kb, const WS& w)
{
  const __hip_bfloat16* ap = &in[j0][kb];
  bf16x8 a0 = *(const bf16x8*)(const void*)(ap);
  bf16x8 a1 = *(const bf16x8*)(const void*)(ap + 32);
  bf16x8 a2 = *(const bf16x8*)(const void*)(ap + 64);
  #pragma unroll
  for (int q = 0; q < 5; q++) acc[q] = (f32x4){w.bias[q], w.bias[q], w.bias[q], w.bias[q]};
  #pragma unroll
  for (int q = 0; q < 5; q++) acc[q] = __builtin_amdgcn_mfma_f32_16x16x32_bf16(a0, w.b[q][0], acc[q], 0, 0, 0);
  #pragma unroll
  for (int q = 0; q < 5; q++) acc[q] = __builtin_amdgcn_mfma_f32_16x16x32_bf16(a1, w.b[q][1], acc[q], 0, 0, 0);
  #pragma unroll
  for (int q = 0; q < 5; q++) acc[q] = __builtin_amdgcn_mfma_f32_16x16x32_bf16(a2, w.b[q][2], acc[q], 0, 0, 0);
}

// One residual block, fully wave-local (no __syncthreads; lgkmcnt orders LDS).
__device__ __forceinline__ void resblk(f32x4 cur[5],
    __hip_bfloat16 (*act)[LDSW], int j0, int kb, int g,
    WS& w1, WS& w2, const __hip_bfloat16* __restrict__ wt,
    int s1n, const float* __restrict__ b1n,
    int s2n, const float* __restrict__ b2n)
{
  f32x4 acc[5];
  mmA(acc, act, j0, kb, w1);            // reads x
  loadWS(w1, wt, s1n, b1n, j0, kb);     // prefetch next use of w1
  #pragma unroll
  for (int q = 0; q < 5; q++)
    #pragma unroll
    for (int i = 0; i < 4; i++)
      act[g*4 + i][16*q + j0] = tob(sp_f(acc[q][i]));   // t = sp(x@W1+b1)
  mmA(acc, act, j0, kb, w2);            // t@W2
  loadWS(w2, wt, s2n, b2n, j0, kb);
  #pragma unroll
  for (int q = 0; q < 5; q++)
    #pragma unroll
    for (int i = 0; i < 4; i++){
      cur[q][i] = sp_f(acc[q][i] + cur[q][i]);          // sp(t@W2+b2+x)
      act[g*4 + i][16*q + j0] = tob(cur[q][i]);
    }
}

// ---------------------------------------------------------------------------
// Atom kernel, wave-autonomous: each wave owns 16 atoms, all 80 cols,
// streams through all 21 layers with zero inner barriers.
// grid = N/64 blocks x 256 threads (4 waves).
// ---------------------------------------------------------------------------
__global__ __launch_bounds__(256, 1) void atom_mfma(
    const int*   __restrict__ species,
    const float* __restrict__ features,
    const unsigned long long* __restrict__ R6u,
    const __hip_bfloat16* __restrict__ wt,
    const float* __restrict__ Wg, const float* __restrict__ bg,
    const float* __restrict__ bJ, const float* __restrict__ bI,
    const float* __restrict__ ib1, const float* __restrict__ ib2,
    const float* __restrict__ gate, const float* __restrict__ bint,
    const float* __restrict__ ab1, const float* __restrict__ ab2,
    const float* __restrict__ ob1, const float* __restrict__ ob2,
    const float* __restrict__ Wout, const float* __restrict__ bout,
    float* __restrict__ out_e, float* __restrict__ out_f)
{
  __shared__ __align__(16) __hip_bfloat16 actS[4][16][LDSW];
  __shared__ __align__(16) __hip_bfloat16 xfbS[4][16][LDSW];
  __shared__ float RlS[4][16][4 * NSLOT];
  __shared__ float WgL[RDIM + 1][FDIM];   // rows 0..19 = Wg, row 20 = bg

  const int t    = threadIdx.x;
  const int lane = t & 63;
  const int w    = t >> 6;
  const int base = blockIdx.x * 64 + w * 16;   // this wave's atom base

  __hip_bfloat16 (*act)[LDSW] = actS[w];
  __hip_bfloat16 (*xfb)[LDSW] = xfbS[w];
  float (*Rl)[4 * NSLOT] = RlS[w];

  const int j0 = lane & 15;
  const int g  = lane >> 4;
  const int kb = g * 8;

  // block-shared Wg/bg table
  for (int i = t; i < (RDIM + 1) * FDIM; i += 256){
    int r = i / FDIM, c = i - r * FDIM;
    WgL[r][c] = (r < RDIM) ? Wg[r * FDIM + c] : bg[c];
  }
  // wave-local staging: features -> xfb (raw), act (softplus)
  #pragma unroll
  for (int it = 0; it < 20; it++){
    int idx = it * 64 + lane;
    int row = idx / FDIM, c = idx - row * FDIM;
    float v = features[(size_t)(base + row) * FDIM + c];
    xfb[row][c] = tob(v);
    act[row][c] = tob(sp_f(v));
  }
  // zero K-pad cols [80,96) in both wave-local tiles
  #pragma unroll
  for (int it = 0; it < 8; it++){
    int idx = it * 64 + lane;
    int row = (idx >> 4) & 15, c = FDIM + (idx & 15);
    if (it < 4) act[row][c] = tob(0.f);
    else        xfb[row][c] = tob(0.f);
  }
  // stage + unpack R (wave-local)
  #pragma unroll
  for (int it = 0; it < 2; it++){
    int idx = it * 64 + lane;
    if (idx < 16 * NSLOT){
      int u = idx / NSLOT, s = idx - u * NSLOT;
      unsigned long long v = R6u[(size_t)(base + u) * NSLOT + s];
      #pragma unroll
      for (int f = 0; f < 4; f++)
        Rl[u][4*s + f] = (float)((unsigned int)(v >> (16*f)) & 0xffffu) * FIX_INV;
    }
  }
  float msk[4];
  #pragma unroll
  for (int i = 0; i < 4; i++)
    msk[i] = (species[base + g*4 + i] != -1) ? 1.f : 0.f;
  float greg[5], wo5[5];
  #pragma unroll
  for (int q = 0; q < 5; q++){ greg[q] = gate[16*q + j0]; wo5[q] = Wout[16*q + j0]; }

  __syncthreads();   // only for WgL (everything else is wave-private)

  WS wA, wB;
  loadWS(wA, wt, 0, bJ, j0, kb);
  loadWS(wB, wt, 1, bI, j0, kb);

  // S = [R|deg] @ [Wg;bg] at this lane's C positions (rows g*4+i, cols 16q+j0)
  f32x4 Sreg[5];
  #pragma unroll
  for (int q = 0; q < 5; q++) Sreg[q] = (f32x4){0.f, 0.f, 0.f, 0.f};
  for (int r = 0; r <= RDIM; r++){
    float rv0 = Rl[g*4+0][r], rv1 = Rl[g*4+1][r], rv2 = Rl[g*4+2][r], rv3 = Rl[g*4+3][r];
    #pragma unroll
    for (int q = 0; q < 5; q++){
      float wv = WgL[r][16*q + j0];
      Sreg[q][0] += rv0 * wv; Sreg[q][1] += rv1 * wv;
      Sreg[q][2] += rv2 * wv; Sreg[q][3] += rv3 * wv;
    }
  }

  f32x4 cur[5];

  // proto = sp(sp(f)@WJ+bJ) * S + (f@WI+bI)*mask
  {
    f32x4 accJ[5], accI[5];
    mmA(accJ, act, j0, kb, wA);
    loadWS(wA, wt, 3, ib1, j0, kb);
    mmA(accI, xfb, j0, kb, wB);
    loadWS(wB, wt, 4, ib2, j0, kb);
    #pragma unroll
    for (int q = 0; q < 5; q++)
      #pragma unroll
      for (int i = 0; i < 4; i++){
        cur[q][i] = sp_f(accJ[q][i]) * Sreg[q][i] + accI[q][i] * msk[i];
        act[g*4 + i][16*q + j0] = tob(cur[q][i]);
      }
  }

  // message = res_stack(proto, iW): slots (3,4),(5,6),(7,8)
  resblk(cur, act, j0, kb, g, wA, wB, wt, 5, ib1 + FDIM,   6, ib2 + FDIM);
  resblk(cur, act, j0, kb, g, wA, wB, wt, 7, ib1 + 2*FDIM, 8, ib2 + 2*FDIM);
  resblk(cur, act, j0, kb, g, wA, wB, wt, 2, bint,         9, ab1);

  // nd = f*gate + sp(message)@Wint + bint   (wA = slot 2)
  {
    #pragma unroll
    for (int q = 0; q < 5; q++)
      #pragma unroll
      for (int i = 0; i < 4; i++)
        act[g*4 + i][16*q + j0] = tob(sp_f(cur[q][i]));
    f32x4 acc[5];
    mmA(acc, act, j0, kb, wA);
    loadWS(wA, wt, 10, ab2, j0, kb);
    #pragma unroll
    for (int q = 0; q < 5; q++)
      #pragma unroll
      for (int i = 0; i < 4; i++){
        float xv = __bfloat162float(xfb[g*4 + i][16*q + j0]);
        cur[q][i] = xv * greg[q] + acc[q][i];
        act[g*4 + i][16*q + j0] = tob(cur[q][i]);
      }
  }

  // nd = res_stack(nd, aW): slots (9,10),(11,12),(13,14)
  resblk(cur, act, j0, kb, g, wB, wA, wt, 11, ab1 + FDIM,   12, ab2 + FDIM);
  resblk(cur, act, j0, kb, g, wB, wA, wt, 13, ab1 + 2*FDIM, 14, ab2 + 2*FDIM);
  resblk(cur, act, j0, kb, g, wB, wA, wt, 15, ob1,          16, ob2);

  // out_features = nd * mask
  #pragma unroll
  for (int q = 0; q < 5; q++)
    #pragma unroll
    for (int i = 0; i < 4; i++)
      out_f[(size_t)(base + g*4 + i) * FDIM + 16*q + j0] = cur[q][i] * msk[i];

  // t3 = res_stack(nd, oW): slots (15,16),(17,18),(19,20)
  resblk(cur, act, j0, kb, g, wB, wA, wt, 17, ob1 + FDIM,   18, ob2 + FDIM);
  resblk(cur, act, j0, kb, g, wB, wA, wt, 19, ob1 + 2*FDIM, 20, ob2 + 2*FDIM);
  resblk(cur, act, j0, kb, g, wB, wA, wt, 0,  bJ,           0,  bJ);  // dummy prefetch

  // energies = (sp(t3) @ Wout + bout) * mask
  {
    f32x4 ev = (f32x4){0.f, 0.f, 0.f, 0.f};
    #pragma unroll
    for (int q = 0; q < 5; q++)
      #pragma unroll
      for (int i = 0; i < 4; i++) ev[i] += sp_f(cur[q][i]) * wo5[q];
    #pragma unroll
    for (int off = 1; off < 16; off <<= 1)
      #pragma unroll
      for (int i = 0; i < 4; i++) ev[i] += __shfl_xor(ev[i], off);
    if (j0 == 0){
      float b0 = bout[0];
      #pragma unroll
      for (int i = 0; i < 4; i++)
        out_e[base + g*4 + i] = (ev[i] + b0) * msk[i];
    }
  }
}

// ---------------------------------------------------------------------------
extern "C" void kernel_launch(void* const* d_in, const int* in_sizes, int n_in,
                              void* d_out, int out_size, void* d_ws, size_t ws_size,
                              hipStream_t stream) {
  const int*   species  = (const int*)  d_in[0];
  const float* features = (const float*)d_in[1];
  const float* aev      = (const float*)d_in[2];
  const int*   idx12    = (const int*)  d_in[3];
  const float* WI   = (const float*)d_in[4];  const float* bI   = (const float*)d_in[5];
  const float* Wg   = (const float*)d_in[6];  const float* bg   = (const float*)d_in[7];
  const float* WJ   = (const float*)d_in[8];  const float* bJ   = (const float*)d_in[9];
  const float* iW1  = (const float*)d_in[10]; const float* ib1  = (const float*)d_in[11];
  const float* iW2  = (const float*)d_in[12]; const float* ib2  = (const float*)d_in[13];
  const float* gate = (const float*)d_in[14];
  const float* Wint = (const float*)d_in[15]; const float* bint = (const float*)d_in[16];
  const float* aW1  = (const float*)d_in[17]; const float* ab1  = (const float*)d_in[18];
  const float* aW2  = (const float*)d_in[19]; const float* ab2  = (const float*)d_in[20];
  const float* oW1  = (const float*)d_in[21]; const float* ob1  = (const float*)d_in[22];
  const float* oW2  = (const float*)d_in[23]; const float* ob2  = (const float*)d_in[24];
  const float* Wout = (const float*)d_in[25]; const float* bout = (const float*)d_in[26];

  const int N = in_sizes[1] / FDIM;   // 16384
  const int P = in_sizes[2] / RDIM;   // 393216

  unsigned long long* R6u = (unsigned long long*)d_ws;              // N*6 u64
  __hip_bfloat16* wt = (__hip_bfloat16*)(R6u + (size_t)N * NSLOT);  // 21*80*96 bf16

  float* out_e = (float*)d_out;
  float* out_f = out_e + N;

  hipMemsetAsync(R6u, 0, (size_t)N * NSLOT * sizeof(unsigned long long), stream);

  WPtrs wp;
  wp.p[0] = WJ; wp.p[1] = WI; wp.p[2] = Wint;
  for (int ir = 0; ir < 3; ir++){
    wp.p[3  + 2*ir] = iW1 + ir*FDIM*FDIM; wp.p[4  + 2*ir] = iW2 + ir*FDIM*FDIM;
    wp.p[9  + 2*ir] = aW1 + ir*FDIM*FDIM; wp.p[10 + 2*ir] = aW2 + ir*FDIM*FDIM;
    wp.p[15 + 2*ir] = oW1 + ir*FDIM*FDIM; wp.p[16 + 2*ir] = oW2 + ir*FDIM*FDIM;
  }
  prep_weights<<<21, 256, 0, stream>>>(wp, wt);

  scatter_p16<<<((size_t)P * NSLOT + 255) / 256, 256, 0, stream>>>(aev, idx12, R6u, P);

  atom_mfma<<<N / 64, 256, 0, stream>>>(species, features, R6u, wt,
      Wg, bg, bJ, bI, ib1, ib2, gate, bint, ab1, ab2, ob1, ob2, Wout, bout,
      out_e, out_f);
}

// Round 10
// 108.428 us; speedup vs baseline: 1.0681x; 1.0681x over previous
//
#include <hip/hip_runtime.h>
#include <hip/hip_bf16.h>

#define FDIM 80
#define RDIM 20
#define RSLOT 5      // u64 slots per atom row: 4 fields x 13 bits each + deg in slot0[52:63]
#define LDP  104     // LDS row stride (bf16)
#define WROW 96      // Wt row stride (bf16), K padded to 96
#define AROWS 16     // atoms per block in atom_mfma

#define FIX_SCALE 64.0f     // 2^6
#define FIX_INV   0.015625f // 2^-6

typedef float  f32x4  __attribute__((ext_vector_type(4)));
typedef short  bf16x8 __attribute__((ext_vector_type(8)));

__device__ __forceinline__ float sp_f(float x){
  float e = __expf(-fabsf(x));
  return fmaxf(x, 0.f) + __logf(1.f + e);
}
__device__ __forceinline__ __hip_bfloat16 tob(float x){ return __float2bfloat16(x); }

// ---------------------------------------------------------------------------
// Weight prep: Wt[slot][j][k] = bf16(W[k][j]), zero-padded k in [80,96)
// ---------------------------------------------------------------------------
struct WPtrs { const float* p[21]; };

__global__ __launch_bounds__(256) void prep_weights(WPtrs wp, __hip_bfloat16* __restrict__ wt){
  const float* W = wp.p[blockIdx.x];
  __hip_bfloat16* dst = wt + (size_t)blockIdx.x * FDIM * WROW;
  for (int i = threadIdx.x; i < FDIM * WROW; i += 256){
    int j = i / WROW, k = i - j * WROW;
    dst[i] = __float2bfloat16(k < FDIM ? W[k * FDIM + j] : 0.f);
  }
}

// ---------------------------------------------------------------------------
// Scatter, 13-bit fixed-point, 4 fields per u64; deg folded into slot0[52:63].
// Field sums <= deg_max*64 ~ 5760 < 8192 -> no cross-field carry.
// ---------------------------------------------------------------------------
__global__ __launch_bounds__(256) void scatter_p13(const float* __restrict__ aev,
    const int* __restrict__ idx12, unsigned long long* __restrict__ R5u, int P)
{
  int g = blockIdx.x * 256 + threadIdx.x;
  if (g >= P * RSLOT) return;
  int p = g / RSLOT, s = g - p * RSLOT;
  float4 a = ((const float4*)(aev + (size_t)p * RDIM))[s];
  unsigned long long f0 = (unsigned long long)__float2uint_rn(a.x * FIX_SCALE);
  unsigned long long f1 = (unsigned long long)__float2uint_rn(a.y * FIX_SCALE);
  unsigned long long f2 = (unsigned long long)__float2uint_rn(a.z * FIX_SCALE);
  unsigned long long f3 = (unsigned long long)__float2uint_rn(a.w * FIX_SCALE);
  unsigned long long v = f0 | (f1 << 13) | (f2 << 26) | (f3 << 39);
  if (s == 0) v |= (1ULL << 52);   // deg increment
  int i1 = idx12[p], i2 = idx12[P + p];
  atomicAdd(&R5u[(size_t)i1 * RSLOT + s], v);
  atomicAdd(&R5u[(size_t)i2 * RSLOT + s], v);
}

// ---------------------------------------------------------------------------
// Weight fragment (one layer's B-operand for this thread) + rolling prefetch
// ---------------------------------------------------------------------------
struct WF { bf16x8 b0, b1, b2; float bias; };

__device__ __forceinline__ WF loadWF(const __hip_bfloat16* __restrict__ wb,
                                     int slot, const float* __restrict__ bias, int row){
  WF w;
  const __hip_bfloat16* p = wb + (size_t)slot * (FDIM * WROW);
  w.b0 = *(const bf16x8*)(const void*)(p);
  w.b1 = *(const bf16x8*)(const void*)(p + 32);
  w.b2 = *(const bf16x8*)(const void*)(p + 64);
  w.bias = bias[row];
  return w;
}

// A-frag: m=lane&15, k=(lane>>4)*8+e (+32ks). C/D: col=lane&15, row=(lane>>4)*4+i.
__device__ __forceinline__ f32x4 mfmaL(
    const __hip_bfloat16 (*in)[LDP], int j0, int kb, const WF& w)
{
  const __hip_bfloat16* ap = &in[j0][kb];
  bf16x8 a0 = *(const bf16x8*)(const void*)(ap);
  bf16x8 a1 = *(const bf16x8*)(const void*)(ap + 32);
  bf16x8 a2 = *(const bf16x8*)(const void*)(ap + 64);
  f32x4 acc = (f32x4){w.bias, w.bias, w.bias, w.bias};
  acc = __builtin_amdgcn_mfma_f32_16x16x32_bf16(a0, w.b0, acc, 0, 0, 0);
  acc = __builtin_amdgcn_mfma_f32_16x16x32_bf16(a1, w.b1, acc, 0, 0, 0);
  acc = __builtin_amdgcn_mfma_f32_16x16x32_bf16(a2, w.b2, acc, 0, 0, 0);
  return acc;
}

// One residual block: uses preloaded w1,w2; prefetches pf1->w1, pf2->w2.
__device__ __forceinline__ void resblk(f32x4& cur,
    __hip_bfloat16 (*bA)[LDP], __hip_bfloat16 (*bB)[LDP],
    int j0, int kb, int g, int col,
    WF& w1, WF& w2,
    const __hip_bfloat16* __restrict__ wb, int row,
    int pf1, const float* __restrict__ pf1b,
    int pf2, const float* __restrict__ pf2b)
{
  f32x4 acc = mfmaL(bA, j0, kb, w1);
  w1 = loadWF(wb, pf1, pf1b, row);
  #pragma unroll
  for (int i = 0; i < 4; i++) bB[g*4 + i][col] = tob(sp_f(acc[i]));
  __syncthreads();
  acc = mfmaL(bB, j0, kb, w2);
  w2 = loadWF(wb, pf2, pf2b, row);
  #pragma unroll
  for (int i = 0; i < 4; i++){
    cur[i] = sp_f(acc[i] + cur[i]);
    bA[g*4 + i][col] = tob(cur[i]);
  }
  __syncthreads();
}

// ---------------------------------------------------------------------------
// Atom kernel: 16 atoms/block, 5 waves (one 16-col block each); S computed
// in-kernel from R5u; rolling weight prefetch. grid = N/16 = 1024 blocks.
// ---------------------------------------------------------------------------
__global__ __launch_bounds__(320, 4) void atom_mfma(
    const int*   __restrict__ species,
    const float* __restrict__ features,
    const unsigned long long* __restrict__ R5u,
    const __hip_bfloat16* __restrict__ wt,
    const float* __restrict__ Wg, const float* __restrict__ bg,
    const float* __restrict__ bJ, const float* __restrict__ bI,
    const float* __restrict__ ib1, const float* __restrict__ ib2,
    const float* __restrict__ gate, const float* __restrict__ bint,
    const float* __restrict__ ab1, const float* __restrict__ ab2,
    const float* __restrict__ ob1, const float* __restrict__ ob2,
    const float* __restrict__ Wout, const float* __restrict__ bout,
    float* __restrict__ out_e, float* __restrict__ out_f)
{
  __shared__ __align__(16) __hip_bfloat16 bufA[AROWS][LDP];
  __shared__ __align__(16) __hip_bfloat16 bufB[AROWS][LDP];
  __shared__ __align__(16) __hip_bfloat16 xfb[AROWS][LDP];
  __shared__ float Rl[AROWS][22];      // 0..19 aev sums, 20 deg
  __shared__ float mskl[AROWS];
  __shared__ float evp[5][AROWS];

  const int t    = threadIdx.x;
  const int lane = t & 63;
  const int nt   = t >> 6;          // 0..4 : output column block
  const int base = blockIdx.x * AROWS;

  const int j0  = lane & 15;
  const int g   = lane >> 4;
  const int kb  = g * 8;
  const int col = 16*nt + j0;
  const int row = col;                       // B-frag row == output col
  const __hip_bfloat16* wb = wt + (size_t)row * WROW + kb;

  // early: Wg column + bg for in-kernel S computation (dead after Sreg)
  float wgc[RDIM + 1];
  #pragma unroll
  for (int r = 0; r < RDIM; r++) wgc[r] = Wg[r * FDIM + col];
  wgc[RDIM] = bg[col];

  // stage features: raw bf16 -> xfb, softplus bf16 -> bufA
  for (int i = t; i < AROWS * FDIM; i += 320){
    int rr = i / FDIM, cc = i - rr * FDIM;
    float v = features[(size_t)(base + rr) * FDIM + cc];
    xfb [rr][cc] = tob(v);
    bufA[rr][cc] = tob(sp_f(v));
  }
  // zero K-pad cols [80,96)
  for (int i = t; i < 3 * AROWS * 16; i += 320){
    int b = i / (AROWS * 16), rem = i % (AROWS * 16);
    int rr = rem >> 4, cc = FDIM + (rem & 15);
    if      (b == 0) bufA[rr][cc] = tob(0.f);
    else if (b == 1) bufB[rr][cc] = tob(0.f);
    else             xfb [rr][cc] = tob(0.f);
  }
  // stage + unpack R (13-bit fields; deg in slot0[52:63])
  if (t < AROWS * RSLOT){
    int u = t / RSLOT, s5 = t - u * RSLOT;
    unsigned long long v = R5u[(size_t)(base + u) * RSLOT + s5];
    #pragma unroll
    for (int f = 0; f < 4; f++)
      Rl[u][4*s5 + f] = (float)((unsigned int)(v >> (13*f)) & 0x1fffu) * FIX_INV;
    if (s5 == 0) Rl[u][RDIM] = (float)((unsigned int)(v >> 52) & 0xfffu);
  }
  if (t < AROWS) mskl[t] = (species[base + t] != -1) ? 1.f : 0.f;
  __syncthreads();

  // S in registers: Sreg[i] for rows g*4+i, column `col`
  f32x4 Sreg;
  #pragma unroll
  for (int i = 0; i < 4; i++){
    int rr = g*4 + i;
    float a = 0.f;
    #pragma unroll
    for (int r = 0; r <= RDIM; r++) a += Rl[rr][r] * wgc[r];
    Sreg[i] = a;
  }

  f32x4 cur;

  // proto = sp(sp(f)@WJ+bJ) * S + (f@WI+bI)*mask   (layers L0,L1)
  {
    WF wA = loadWF(wb, 0, bJ, row);
    WF wB = loadWF(wb, 1, bI, row);
    f32x4 aJ = mfmaL(bufA, j0, kb, wA);  wA = loadWF(wb, 3, ib1, row);
    f32x4 aI = mfmaL(xfb , j0, kb, wB);  wB = loadWF(wb, 4, ib2, row);
    __syncthreads();   // bufA reads done before overwrite
    #pragma unroll
    for (int i = 0; i < 4; i++){
      cur[i] = sp_f(aJ[i]) * Sreg[i] + aI[i] * mskl[g*4 + i];
      bufA[g*4 + i][col] = tob(cur[i]);
    }
    __syncthreads();

    // message = res_stack(proto, iW): slots (3,4),(5,6),(7,8)
    resblk(cur, bufA, bufB, j0, kb, g, col, wA, wB, wb, row,
           5, ib1 + FDIM,     6, ib2 + FDIM);
    resblk(cur, bufA, bufB, j0, kb, g, col, wA, wB, wb, row,
           7, ib1 + 2*FDIM,   8, ib2 + 2*FDIM);
    resblk(cur, bufA, bufB, j0, kb, g, col, wA, wB, wb, row,
           2, bint,           9, ab1);

    // nd = f*gate + sp(message)@Wint + bint   (layer L8, uses wA=slot2)
    #pragma unroll
    for (int i = 0; i < 4; i++) bufB[g*4 + i][col] = tob(sp_f(cur[i]));
    __syncthreads();
    {
      f32x4 acc = mfmaL(bufB, j0, kb, wA);
      wA = loadWF(wb, 10, ab2, row);
      float gj = gate[col];
      #pragma unroll
      for (int i = 0; i < 4; i++){
        float xv = __bfloat162float(xfb[g*4 + i][col]);
        cur[i] = xv * gj + acc[i];
        bufA[g*4 + i][col] = tob(cur[i]);
      }
    }
    __syncthreads();

    // nd = res_stack(nd, aW): slots (9,10),(11,12),(13,14)  [w1=wB, w2=wA]
    resblk(cur, bufA, bufB, j0, kb, g, col, wB, wA, wb, row,
           11, ab1 + FDIM,    12, ab2 + FDIM);
    resblk(cur, bufA, bufB, j0, kb, g, col, wB, wA, wb, row,
           13, ab1 + 2*FDIM,  14, ab2 + 2*FDIM);
    resblk(cur, bufA, bufB, j0, kb, g, col, wB, wA, wb, row,
           15, ob1,           16, ob2);

    // out_features = nd * mask
    #pragma unroll
    for (int i = 0; i < 4; i++)
      out_f[(size_t)(base + g*4 + i) * FDIM + col] = cur[i] * mskl[g*4 + i];

    // t3 = res_stack(nd, oW): slots (15,16),(17,18),(19,20)
    resblk(cur, bufA, bufB, j0, kb, g, col, wB, wA, wb, row,
           17, ob1 + FDIM,    18, ob2 + FDIM);
    resblk(cur, bufA, bufB, j0, kb, g, col, wB, wA, wb, row,
           19, ob1 + 2*FDIM,  20, ob2 + 2*FDIM);
    resblk(cur, bufA, bufB, j0, kb, g, col, wB, wA, wb, row,
           0, bJ,             0, bJ);   // dummy prefetch
  }

  // energies = (sp(t3) @ Wout + bout) * mask
  {
    float wv = Wout[col];
    float ev[4];
    #pragma unroll
    for (int i = 0; i < 4; i++) ev[i] = sp_f(cur[i]) * wv;
    #pragma unroll
    for (int off = 1; off < 16; off <<= 1){
      #pragma unroll
      for (int i = 0; i < 4; i++) ev[i] += __shfl_xor(ev[i], off);
    }
    if (j0 == 0){
      #pragma unroll
      for (int i = 0; i < 4; i++) evp[nt][g*4 + i] = ev[i];
    }
  }
  __syncthreads();
  if (t < AROWS)
    out_e[base + t] = (evp[0][t] + evp[1][t] + evp[2][t] + evp[3][t] + evp[4][t]
                       + bout[0]) * mskl[t];
}

// ---------------------------------------------------------------------------
extern "C" void kernel_launch(void* const* d_in, const int* in_sizes, int n_in,
                              void* d_out, int out_size, void* d_ws, size_t ws_size,
                              hipStream_t stream) {
  const int*   species  = (const int*)  d_in[0];
  const float* features = (const float*)d_in[1];
  const float* aev      = (const float*)d_in[2];
  const int*   idx12    = (const int*)  d_in[3];
  const float* WI   = (const float*)d_in[4];  const float* bI   = (const float*)d_in[5];
  const float* Wg   = (const float*)d_in[6];  const float* bg   = (const float*)d_in[7];
  const float* WJ   = (const float*)d_in[8];  const float* bJ   = (const float*)d_in[9];
  const float* iW1  = (const float*)d_in[10]; const float* ib1  = (const float*)d_in[11];
  const float* iW2  = (const float*)d_in[12]; const float* ib2  = (const float*)d_in[13];
  const float* gate = (const float*)d_in[14];
  const float* Wint = (const float*)d_in[15]; const float* bint = (const float*)d_in[16];
  const float* aW1  = (const float*)d_in[17]; const float* ab1  = (const float*)d_in[18];
  const float* aW2  = (const float*)d_in[19]; const float* ab2  = (const float*)d_in[20];
  const float* oW1  = (const float*)d_in[21]; const float* ob1  = (const float*)d_in[22];
  const float* oW2  = (const float*)d_in[23]; const float* ob2  = (const float*)d_in[24];
  const float* Wout = (const float*)d_in[25]; const float* bout = (const float*)d_in[26];

  const int N = in_sizes[1] / FDIM;   // 16384
  const int P = in_sizes[2] / RDIM;   // 393216

  unsigned long long* R5u = (unsigned long long*)d_ws;              // N*5 u64
  __hip_bfloat16* wt = (__hip_bfloat16*)(R5u + (size_t)N * RSLOT);  // 21*80*96 bf16

  float* out_e = (float*)d_out;
  float* out_f = out_e + N;

  hipMemsetAsync(R5u, 0, (size_t)N * RSLOT * sizeof(unsigned long long), stream);

  WPtrs wp;
  wp.p[0] = WJ; wp.p[1] = WI; wp.p[2] = Wint;
  for (int ir = 0; ir < 3; ir++){
    wp.p[3  + 2*ir] = iW1 + ir*FDIM*FDIM; wp.p[4  + 2*ir] = iW2 + ir*FDIM*FDIM;
    wp.p[9  + 2*ir] = aW1 + ir*FDIM*FDIM; wp.p[10 + 2*ir] = aW2 + ir*FDIM*FDIM;
    wp.p[15 + 2*ir] = oW1 + ir*FDIM*FDIM; wp.p[16 + 2*ir] = oW2 + ir*FDIM*FDIM;
  }
  prep_weights<<<21, 256, 0, stream>>>(wp, wt);

  scatter_p13<<<((size_t)P * RSLOT + 255) / 256, 256, 0, stream>>>(aev, idx12, R5u, P);

  atom_mfma<<<(N + AROWS - 1) / AROWS, 320, 0, stream>>>(species, features, R5u, wt,
      Wg, bg, bJ, bI, ib1, ib2, gate, bint, ab1, ab2, ob1, ob2, Wout, bout,
      out_e, out_f);
}